// Round 11
// baseline (29.880 us; speedup 1.0000x reference)
//
#include <hip/hip_runtime.h>

typedef float v2f __attribute__((ext_vector_type(2)));

#define FEPS 1e-16f
#define LOG_2PI 1.8378770664093453f
#define DUMMYV -4.605170185988091f   /* -2*log(10) */
#define LOG2E 1.4426950408889634f
#define LN2 0.6931471805599453f

constexpr int B = 32, N = 1024, V = 512;
constexpr int ROWS_PER_BLOCK = 16;           // R11 single knob: was 32 (R4 best)
constexpr int GRID_X = N / ROWS_PER_BLOCK;   // 64 -> 2048 blocks

constexpr long long OFF_LOGPROB    = 0;
constexpr long long OFF_VOTEPRES   = 1;
constexpr long long OFF_WINNER     = OFF_VOTEPRES + (long long)B * V;
constexpr long long OFF_WINNERPRES = OFF_WINNER + (long long)B * N * 4;
constexpr long long OFF_ISFROM     = OFF_WINNERPRES + (long long)B * N;
constexpr long long OFF_MLOGITS    = OFF_ISFROM + (long long)B * N;
constexpr long long OFF_MLOGPROB   = OFF_MLOGITS + (long long)B * (V + 1);
constexpr long long OFF_ZW         = OFF_MLOGPROB + (long long)B * (V + 1);
constexpr long long OFF_ZWP        = OFF_ZW + (long long)B * N * 4;
constexpr long long OFF_PMP        = OFF_ZWP + (long long)B * N;

__device__ __forceinline__ float fexp2(float x) {
#if __has_builtin(__builtin_amdgcn_exp2f)
    return __builtin_amdgcn_exp2f(x);
#else
    return __expf(x * LN2);
#endif
}
__device__ __forceinline__ float frcp(float x) {
#if __has_builtin(__builtin_amdgcn_rcpf)
    return __builtin_amdgcn_rcpf(x);
#else
    return 1.0f / x;
#endif
}

template<int RN> __device__ __forceinline__ float dppRorF(float x) {
    return __int_as_float(__builtin_amdgcn_update_dpp(
        0, __float_as_int(x), 0x120 | RN, 0xF, 0xF, false));
}
template<int RN> __device__ __forceinline__ int dppRorI(int x) {
    return __builtin_amdgcn_update_dpp(0, x, 0x120 | RN, 0xF, 0xF, false);
}
// xor-16 butterfly step via ds_swizzle bitmode: offset = (16<<10)|0x1F
__device__ __forceinline__ float swz16F(float x) {
    return __int_as_float(__builtin_amdgcn_ds_swizzle(__float_as_int(x), 0x401F));
}
__device__ __forceinline__ int swz16I(int x) {
    return __builtin_amdgcn_ds_swizzle(x, 0x401F);
}

// xor-32 step: permlane32_swap (VALU pipe) if available, else shfl (LDS pipe)
#if __has_builtin(__builtin_amdgcn_permlane32_swap)
__device__ __forceinline__ float maxSwap32(float x) {
    auto r = __builtin_amdgcn_permlane32_swap(__float_as_uint(x), __float_as_uint(x), false, false);
    return fmaxf(__uint_as_float(r[0]), __uint_as_float(r[1]));
}
__device__ __forceinline__ float sumSwap32(float x) {
    auto r = __builtin_amdgcn_permlane32_swap(__float_as_uint(x), __float_as_uint(x), false, false);
    return __uint_as_float(r[0]) + __uint_as_float(r[1]);
}
__device__ __forceinline__ int minSwap32(int x) {
    auto r = __builtin_amdgcn_permlane32_swap((unsigned)x, (unsigned)x, false, false);
    int a = (int)r[0], b = (int)r[1];
    return a < b ? a : b;
}
#else
__device__ __forceinline__ float maxSwap32(float x) { return fmaxf(x, __shfl_xor(x, 32)); }
__device__ __forceinline__ float sumSwap32(float x) { return x + __shfl_xor(x, 32); }
__device__ __forceinline__ int   minSwap32(int x)   { int o = __shfl_xor(x, 32); return o < x ? o : x; }
#endif

__device__ __forceinline__ float waveMaxF(float m) {
    m = fmaxf(m, dppRorF<1>(m));
    m = fmaxf(m, dppRorF<2>(m));
    m = fmaxf(m, dppRorF<4>(m));
    m = fmaxf(m, dppRorF<8>(m));
    m = fmaxf(m, swz16F(m));
    return maxSwap32(m);
}
__device__ __forceinline__ float waveSumF(float s) {
    s += dppRorF<1>(s);
    s += dppRorF<2>(s);
    s += dppRorF<4>(s);
    s += dppRorF<8>(s);
    s += swz16F(s);
    return sumSwap32(s);
}
__device__ __forceinline__ int waveMinI(int v) {
    int o;
    o = dppRorI<1>(v); v = o < v ? o : v;
    o = dppRorI<2>(v); v = o < v ? o : v;
    o = dppRorI<4>(v); v = o < v ? o : v;
    o = dppRorI<8>(v); v = o < v ? o : v;
    o = swz16I(v);     v = o < v ? o : v;
    return minSwap32(v);
}

__global__ __launch_bounds__(256) void k_fused(const float* __restrict__ x,
                                               const float* __restrict__ votes,
                                               const float* __restrict__ scales,
                                               const float* __restrict__ vpp,
                                               const float* __restrict__ presence,
                                               const int* __restrict__ nvp,
                                               float* __restrict__ out,
                                               float* __restrict__ ws) {
    __shared__ float s_part[4];
    const int b = blockIdx.y, t = threadIdx.x, w = t >> 6, lane = t & 63;
    const long long bV = (long long)b * V;
    const float4* votes4 = reinterpret_cast<const float4*>(votes) + bV;

    // ---- prologue: per-lane votes v = k*64 + lane. Every wave loads ALL
    // 512 votes (redundant but coalesced); wave-level reductions are full.
    float lg[8], lsv[8];
    float4 vt[8];
    #pragma unroll
    for (int k = 0; k < 8; ++k) {
        int v = k * 64 + lane;
        vt[k]  = votes4[v];
        lsv[k] = scales[bV + v];
        lg[k]  = __logf(vpp[bV + v] + FEPS);
    }

    // ---- per-wave LSE over 513 mixing logits ----
    float mm = lg[0];
    #pragma unroll
    for (int k = 1; k < 8; ++k) mm = fmaxf(mm, lg[k]);
    float M = fmaxf(waveMaxF(mm), DUMMYV);
    float ss = 0.f;
    #pragma unroll
    for (int k = 0; k < 8; ++k) ss += __expf(lg[k] - M);
    float S = waveSumF(ss) + __expf(DUMMYV - M);
    float lse = M + __logf(S);
    float dummy_post = DUMMYV + (DUMMYV - lse);

    // ---- mixing outputs (blockIdx.x == 0, wave 0 only) ----
    if (blockIdx.x == 0 && w == 0) {
        #pragma unroll
        for (int k = 0; k < 8; ++k) {
            int v = k * 64 + lane;
            out[OFF_MLOGITS  + (long long)b * (V + 1) + v] = lg[k];
            out[OFF_MLOGPROB + (long long)b * (V + 1) + v] = lg[k] - lse;
            out[OFF_VOTEPRES + bV + v] = (lg[k] > DUMMYV) ? 1.0f : 0.0f;
        }
        if (lane == 0) {
            out[OFF_MLOGITS  + (long long)b * (V + 1) + V] = DUMMYV;
            out[OFF_MLOGPROB + (long long)b * (V + 1) + V] = DUMMYV - lse;
        }
    }

    // ---- per-lane constants in log2 domain, dummy_post absorbed ----
    v2f c2[4], hk[4], hvx[4], hvy[4], hvz[4], hvw[4];
    #pragma unroll
    for (int i = 0; i < 4; ++i) {
        float cc[2], kk[2], ax[2], ay[2], az[2], aw[2];
        #pragma unroll
        for (int h = 0; h < 2; ++h) {
            int k = 2 * i + h;
            float sv  = lsv[k];
            float inv = frcp(sv);
            float hh  = 0.5f * inv * inv;
            float c   = lg[k] - 4.0f * __logf(sv) - 2.0f * LOG_2PI - lse;
            float4 vv = vt[k];
            float v2  = vv.x * vv.x + vv.y * vv.y + vv.z * vv.z + vv.w * vv.w;
            cc[h] = (c - hh * v2 - dummy_post) * LOG2E;
            kk[h] = -hh * LOG2E;
            float g = 2.0f * hh * LOG2E;
            ax[h] = g * vv.x; ay[h] = g * vv.y; az[h] = g * vv.z; aw[h] = g * vv.w;
        }
        c2[i].x = cc[0];  c2[i].y = cc[1];
        hk[i].x = kk[0];  hk[i].y = kk[1];
        hvx[i].x = ax[0]; hvx[i].y = ax[1];
        hvy[i].x = ay[0]; hvy[i].y = ay[1];
        hvz[i].x = az[0]; hvz[i].y = az[1];
        hvw[i].x = aw[0]; hvw[i].y = aw[1];
    }

    const float4* x4 = reinterpret_cast<const float4*>(x) + (long long)b * N;
    int nv = nvp[0];
    float acc = 0.f;   // lane 0 only

    #pragma unroll 2
    for (int iter = 0; iter < ROWS_PER_BLOCK / 4; ++iter) {
        int n = blockIdx.x * ROWS_PER_BLOCK + iter * 4 + w;
        long long bn = (long long)b * N + n;
        float4 xv = x4[n];
        float px2 = xv.x * xv.x + xv.y * xv.y + xv.z * xv.z + xv.w * xv.w;
        v2f P2; P2.x = px2;  P2.y = px2;
        v2f Xx; Xx.x = xv.x; Xx.y = xv.x;
        v2f Xy; Xy.x = xv.y; Xy.y = xv.y;
        v2f Xz; Xz.x = xv.z; Xz.y = xv.z;
        v2f Xw; Xw.x = xv.w; Xw.y = xv.w;

        float p2s[8];
        #pragma unroll
        for (int i = 0; i < 4; ++i) {
            v2f tt = c2[i];
            tt += hk[i]  * P2;
            tt += hvx[i] * Xx;
            tt += hvy[i] * Xy;
            tt += hvz[i] * Xz;
            tt += hvw[i] * Xw;
            p2s[2 * i]     = tt.x;
            p2s[2 * i + 1] = tt.y;
        }

        // row max (value only; exp uses fixed shift)
        float t1 = fmaxf(fmaxf(p2s[0], p2s[1]), p2s[2]);
        float t2 = fmaxf(fmaxf(p2s[3], p2s[4]), p2s[5]);
        float t3 = fmaxf(fmaxf(p2s[6], p2s[7]), t1);
        float Mrow = waveMaxF(fmaxf(t2, t3));

        // exact first-occurrence argmax: min true-vote-index among maxima
        int cand = 0x7fffffff;
        #pragma unroll
        for (int k = 0; k < 8; ++k)
            if (p2s[k] == Mrow && (k * 64 + lane) < cand) cand = k * 64 + lane;
        int bi = waveMinI(cand);

        // fixed-shift softmax (dummy term = exp2(0) = 1)
        float e[8];
        float se = 0.f;
        #pragma unroll
        for (int k = 0; k < 8; ++k) { e[k] = fexp2(p2s[k]); se += e[k]; }
        se = waveSumF(se);
        float total = se + 1.0f;
        float rt = frcp(total);

        long long pb = OFF_PMP + bn * (long long)V;
        #pragma unroll
        for (int k = 0; k < 8; ++k)
            out[pb + k * 64 + lane] = e[k] * rt;   // 256B contiguous per instr

        if (lane == 0) {
            acc += (dummy_post + LN2 * __log2f(total)) * presence[bn];
            float4 wv = votes4[bi];
            out[OFF_WINNER + bn * 4 + 0] = wv.x;
            out[OFF_WINNER + bn * 4 + 1] = wv.y;
            out[OFF_WINNER + bn * 4 + 2] = wv.z;
            out[OFF_WINNER + bn * 4 + 3] = wv.w;
            out[OFF_WINNERPRES + bn]     = vpp[bV + bi];
            out[OFF_ISFROM + bn]         = (float)((nv == 16) ? (bi >> 4) : (bi / nv));
        }
        if (lane == 1) {
            out[OFF_ZW + bn * 4 + 0] = 0.f;
            out[OFF_ZW + bn * 4 + 1] = 0.f;
            out[OFF_ZW + bn * 4 + 2] = 0.f;
            out[OFF_ZW + bn * 4 + 3] = 0.f;
            out[OFF_ZWP + bn]        = 0.f;
        }
    }

    if (lane == 0) s_part[w] = acc;
    __syncthreads();
    if (t == 0)
        ws[(long long)b * gridDim.x + blockIdx.x] =
            s_part[0] + s_part[1] + s_part[2] + s_part[3];
}

__global__ __launch_bounds__(256) void k_reduce(const float* __restrict__ ws,
                                                float* __restrict__ out, int count) {
    __shared__ float sred[256];
    int t = threadIdx.x;
    float s = 0.f;
    for (int i = t; i < count; i += 256) s += ws[i];
    sred[t] = s;
    __syncthreads();
    for (int o = 128; o > 0; o >>= 1) {
        if (t < o) sred[t] += sred[t + o];
        __syncthreads();
    }
    if (t == 0) out[OFF_LOGPROB] = sred[0];
}

extern "C" void kernel_launch(void* const* d_in, const int* in_sizes, int n_in,
                              void* d_out, int out_size, void* d_ws, size_t ws_size,
                              hipStream_t stream) {
    const float* x        = (const float*)d_in[0];
    const float* votes    = (const float*)d_in[1];
    const float* scales   = (const float*)d_in[2];
    const float* vpp      = (const float*)d_in[3];
    const float* presence = (const float*)d_in[4];
    const int*   nv       = (const int*)d_in[5];
    float* out = (float*)d_out;
    float* ws  = (float*)d_ws;

    dim3 g(GRID_X, B);
    k_fused<<<g, 256, 0, stream>>>(x, votes, scales, vpp, presence, nv, out, ws);
    k_reduce<<<1, 256, 0, stream>>>(ws, out, GRID_X * B);
}

// Round 12
// 26.533 us; speedup vs baseline: 1.1262x; 1.1262x over previous
//
#include <hip/hip_runtime.h>

typedef float v2f __attribute__((ext_vector_type(2)));

#define FEPS 1e-16f
#define LOG_2PI 1.8378770664093453f
#define DUMMYV -4.605170185988091f   /* -2*log(10) */
#define LOG2E 1.4426950408889634f
#define LN2 0.6931471805599453f

constexpr int B = 32, N = 1024, V = 512;
constexpr int ROWS_PER_BLOCK = 32;
constexpr int GRID_X = N / ROWS_PER_BLOCK;   // 32 -> 1024 blocks (R4-proven)

constexpr long long OFF_LOGPROB    = 0;
constexpr long long OFF_VOTEPRES   = 1;
constexpr long long OFF_WINNER     = OFF_VOTEPRES + (long long)B * V;
constexpr long long OFF_WINNERPRES = OFF_WINNER + (long long)B * N * 4;
constexpr long long OFF_ISFROM     = OFF_WINNERPRES + (long long)B * N;
constexpr long long OFF_MLOGITS    = OFF_ISFROM + (long long)B * N;
constexpr long long OFF_MLOGPROB   = OFF_MLOGITS + (long long)B * (V + 1);
constexpr long long OFF_ZW         = OFF_MLOGPROB + (long long)B * (V + 1);
constexpr long long OFF_ZWP       = OFF_ZW + (long long)B * N * 4;
constexpr long long OFF_PMP        = OFF_ZWP + (long long)B * N;

__device__ __forceinline__ float fexp2(float x) {
#if __has_builtin(__builtin_amdgcn_exp2f)
    return __builtin_amdgcn_exp2f(x);
#else
    return __expf(x * LN2);
#endif
}
__device__ __forceinline__ float frcp(float x) {
#if __has_builtin(__builtin_amdgcn_rcpf)
    return __builtin_amdgcn_rcpf(x);
#else
    return 1.0f / x;
#endif
}

template<int RN> __device__ __forceinline__ float dppRorF(float x) {
    return __int_as_float(__builtin_amdgcn_update_dpp(
        0, __float_as_int(x), 0x120 | RN, 0xF, 0xF, false));
}
template<int RN> __device__ __forceinline__ int dppRorI(int x) {
    return __builtin_amdgcn_update_dpp(0, x, 0x120 | RN, 0xF, 0xF, false);
}
// xor-16 butterfly step via ds_swizzle bitmode: offset = (16<<10)|0x1F
__device__ __forceinline__ float swz16F(float x) {
    return __int_as_float(__builtin_amdgcn_ds_swizzle(__float_as_int(x), 0x401F));
}
__device__ __forceinline__ int swz16I(int x) {
    return __builtin_amdgcn_ds_swizzle(x, 0x401F);
}

// xor-32 step: permlane32_swap (VALU pipe) if available, else shfl (LDS pipe)
#if __has_builtin(__builtin_amdgcn_permlane32_swap)
__device__ __forceinline__ float maxSwap32(float x) {
    auto r = __builtin_amdgcn_permlane32_swap(__float_as_uint(x), __float_as_uint(x), false, false);
    return fmaxf(__uint_as_float(r[0]), __uint_as_float(r[1]));
}
__device__ __forceinline__ float sumSwap32(float x) {
    auto r = __builtin_amdgcn_permlane32_swap(__float_as_uint(x), __float_as_uint(x), false, false);
    return __uint_as_float(r[0]) + __uint_as_float(r[1]);
}
__device__ __forceinline__ int minSwap32(int x) {
    auto r = __builtin_amdgcn_permlane32_swap((unsigned)x, (unsigned)x, false, false);
    int a = (int)r[0], b = (int)r[1];
    return a < b ? a : b;
}
#else
__device__ __forceinline__ float maxSwap32(float x) { return fmaxf(x, __shfl_xor(x, 32)); }
__device__ __forceinline__ float sumSwap32(float x) { return x + __shfl_xor(x, 32); }
__device__ __forceinline__ int   minSwap32(int x)   { int o = __shfl_xor(x, 32); return o < x ? o : x; }
#endif

__device__ __forceinline__ float waveMaxF(float m) {
    m = fmaxf(m, dppRorF<1>(m));
    m = fmaxf(m, dppRorF<2>(m));
    m = fmaxf(m, dppRorF<4>(m));
    m = fmaxf(m, dppRorF<8>(m));
    m = fmaxf(m, swz16F(m));
    return maxSwap32(m);
}
__device__ __forceinline__ float waveSumF(float s) {
    s += dppRorF<1>(s);
    s += dppRorF<2>(s);
    s += dppRorF<4>(s);
    s += dppRorF<8>(s);
    s += swz16F(s);
    return sumSwap32(s);
}
__device__ __forceinline__ int waveMinI(int v) {
    int o;
    o = dppRorI<1>(v); v = o < v ? o : v;
    o = dppRorI<2>(v); v = o < v ? o : v;
    o = dppRorI<4>(v); v = o < v ? o : v;
    o = dppRorI<8>(v); v = o < v ? o : v;
    o = swz16I(v);     v = o < v ? o : v;
    return minSwap32(v);
}

// R12 = R8's coop-prologue/LDS-coeff kernel WITHOUT the fence/atomic ending
// (that fence was R8's 10x regression: 69.5MB/98us = 709 GB/s write path).
__global__ __launch_bounds__(256) void k_fused(const float* __restrict__ x,
                                               const float* __restrict__ votes,
                                               const float* __restrict__ scales,
                                               const float* __restrict__ vpp,
                                               const float* __restrict__ presence,
                                               const int* __restrict__ nvp,
                                               float* __restrict__ out,
                                               float* __restrict__ ws) {
    // 6 coeff arrays, layout [i=k>>1][lane][h=k&1] so each lane's pair
    // (k=2i,k=2i+1) is one 2-way-aliased (free) ds_read_b64.
    __shared__ float s_c2[512], s_hk[512], s_ax[512], s_ay[512], s_az[512], s_aw[512];
    __shared__ float s_m[4], s_s[4], s_part[4];

    const int b = blockIdx.y, t = threadIdx.x, w = t >> 6, lane = t & 63;
    const long long bV = (long long)b * V;
    const float4* votes4 = reinterpret_cast<const float4*>(votes) + bV;

    // ---- cooperative prologue: this thread owns votes va, vb (coalesced) ----
    const int va = w * 128 + lane, vb = va + 64;
    float4 v4a = votes4[va], v4b = votes4[vb];
    float sva = scales[bV + va], svb = scales[bV + vb];
    float lga = __logf(vpp[bV + va] + FEPS);
    float lgb = __logf(vpp[bV + vb] + FEPS);

    // block LSE over 513 mixing logits
    float mm = waveMaxF(fmaxf(lga, lgb));
    if (lane == 0) s_m[w] = mm;
    __syncthreads();
    float M = fmaxf(fmaxf(fmaxf(s_m[0], s_m[1]), fmaxf(s_m[2], s_m[3])), DUMMYV);
    float ss = waveSumF(__expf(lga - M) + __expf(lgb - M));
    if (lane == 0) s_s[w] = ss;
    __syncthreads();
    float S = s_s[0] + s_s[1] + s_s[2] + s_s[3] + __expf(DUMMYV - M);
    float lse = M + __logf(S);
    float dummy_post = DUMMYV + (DUMMYV - lse);

    // coefficients -> LDS (2 votes per thread)
    {
        float4 vv = v4a;
        float inv = frcp(sva);
        float hh = 0.5f * inv * inv;
        float c = lga - 4.0f * __logf(sva) - 2.0f * LOG_2PI - lse;
        float v2 = vv.x * vv.x + vv.y * vv.y + vv.z * vv.z + vv.w * vv.w;
        int idx = ((va >> 7) << 7) + ((va & 63) << 1) + ((va >> 6) & 1);
        float g = 2.0f * hh * LOG2E;
        s_c2[idx] = (c - hh * v2 - dummy_post) * LOG2E;
        s_hk[idx] = -hh * LOG2E;
        s_ax[idx] = g * vv.x; s_ay[idx] = g * vv.y;
        s_az[idx] = g * vv.z; s_aw[idx] = g * vv.w;
    }
    {
        float4 vv = v4b;
        float inv = frcp(svb);
        float hh = 0.5f * inv * inv;
        float c = lgb - 4.0f * __logf(svb) - 2.0f * LOG_2PI - lse;
        float v2 = vv.x * vv.x + vv.y * vv.y + vv.z * vv.z + vv.w * vv.w;
        int idx = ((vb >> 7) << 7) + ((vb & 63) << 1) + ((vb >> 6) & 1);
        float g = 2.0f * hh * LOG2E;
        s_c2[idx] = (c - hh * v2 - dummy_post) * LOG2E;
        s_hk[idx] = -hh * LOG2E;
        s_ax[idx] = g * vv.x; s_ay[idx] = g * vv.y;
        s_az[idx] = g * vv.z; s_aw[idx] = g * vv.w;
    }

    // mixing outputs (block column 0 only; each thread its 2 votes)
    if (blockIdx.x == 0) {
        long long mb = (long long)b * (V + 1);
        out[OFF_MLOGITS  + mb + va] = lga;
        out[OFF_MLOGITS  + mb + vb] = lgb;
        out[OFF_MLOGPROB + mb + va] = lga - lse;
        out[OFF_MLOGPROB + mb + vb] = lgb - lse;
        out[OFF_VOTEPRES + bV + va] = (lga > DUMMYV) ? 1.0f : 0.0f;
        out[OFF_VOTEPRES + bV + vb] = (lgb > DUMMYV) ? 1.0f : 0.0f;
        if (t == 0) {
            out[OFF_MLOGITS  + mb + V] = DUMMYV;
            out[OFF_MLOGPROB + mb + V] = DUMMYV - lse;
        }
    }
    __syncthreads();

    // ---- per-lane packed constants from LDS (ownership v = k*64 + lane) ----
    v2f c2[4], hk[4], hvx[4], hvy[4], hvz[4], hvw[4];
    #pragma unroll
    for (int i = 0; i < 4; ++i) {
        int o = i * 128 + lane * 2;
        c2[i]  = *reinterpret_cast<const v2f*>(&s_c2[o]);
        hk[i]  = *reinterpret_cast<const v2f*>(&s_hk[o]);
        hvx[i] = *reinterpret_cast<const v2f*>(&s_ax[o]);
        hvy[i] = *reinterpret_cast<const v2f*>(&s_ay[o]);
        hvz[i] = *reinterpret_cast<const v2f*>(&s_az[o]);
        hvw[i] = *reinterpret_cast<const v2f*>(&s_aw[o]);
    }

    const float4* x4 = reinterpret_cast<const float4*>(x) + (long long)b * N;
    int nv = nvp[0];
    float acc = 0.f;   // lane 0 only

    #pragma unroll 2
    for (int iter = 0; iter < ROWS_PER_BLOCK / 4; ++iter) {
        int n = blockIdx.x * ROWS_PER_BLOCK + iter * 4 + w;
        long long bn = (long long)b * N + n;
        float4 xv = x4[n];
        float px2 = xv.x * xv.x + xv.y * xv.y + xv.z * xv.z + xv.w * xv.w;
        v2f P2; P2.x = px2;  P2.y = px2;
        v2f Xx; Xx.x = xv.x; Xx.y = xv.x;
        v2f Xy; Xy.x = xv.y; Xy.y = xv.y;
        v2f Xz; Xz.x = xv.z; Xz.y = xv.z;
        v2f Xw; Xw.x = xv.w; Xw.y = xv.w;

        float p2s[8];
        #pragma unroll
        for (int i = 0; i < 4; ++i) {
            v2f tt = c2[i];
            tt += hk[i]  * P2;
            tt += hvx[i] * Xx;
            tt += hvy[i] * Xy;
            tt += hvz[i] * Xz;
            tt += hvw[i] * Xw;
            p2s[2 * i]     = tt.x;
            p2s[2 * i + 1] = tt.y;
        }

        // row max (value only; exp uses fixed shift)
        float t1 = fmaxf(fmaxf(p2s[0], p2s[1]), p2s[2]);
        float t2 = fmaxf(fmaxf(p2s[3], p2s[4]), p2s[5]);
        float t3 = fmaxf(fmaxf(p2s[6], p2s[7]), t1);
        float Mrow = waveMaxF(fmaxf(t2, t3));

        // exact first-occurrence argmax: min true-vote-index among maxima
        int cand = 0x7fffffff;
        #pragma unroll
        for (int k = 0; k < 8; ++k)
            if (p2s[k] == Mrow && (k * 64 + lane) < cand) cand = k * 64 + lane;
        int bi = waveMinI(cand);

        // fixed-shift softmax (dummy term = exp2(0) = 1)
        float e[8];
        float se = 0.f;
        #pragma unroll
        for (int k = 0; k < 8; ++k) { e[k] = fexp2(p2s[k]); se += e[k]; }
        se = waveSumF(se);
        float total = se + 1.0f;
        float rt = frcp(total);

        long long pb = OFF_PMP + bn * (long long)V;
        #pragma unroll
        for (int k = 0; k < 8; ++k)
            out[pb + k * 64 + lane] = e[k] * rt;   // 256B contiguous per instr

        if (lane == 0) {
            acc += (dummy_post + LN2 * __log2f(total)) * presence[bn];
            float4 wv = votes4[bi];
            out[OFF_WINNER + bn * 4 + 0] = wv.x;
            out[OFF_WINNER + bn * 4 + 1] = wv.y;
            out[OFF_WINNER + bn * 4 + 2] = wv.z;
            out[OFF_WINNER + bn * 4 + 3] = wv.w;
            out[OFF_WINNERPRES + bn]     = vpp[bV + bi];
            out[OFF_ISFROM + bn]         = (float)((nv == 16) ? (bi >> 4) : (bi / nv));
        }
        if (lane == 1) {
            out[OFF_ZW + bn * 4 + 0] = 0.f;
            out[OFF_ZW + bn * 4 + 1] = 0.f;
            out[OFF_ZW + bn * 4 + 2] = 0.f;
            out[OFF_ZW + bn * 4 + 3] = 0.f;
            out[OFF_ZWP + bn]        = 0.f;
        }
    }

    if (lane == 0) s_part[w] = acc;
    __syncthreads();
    if (t == 0)
        ws[(long long)b * gridDim.x + blockIdx.x] =
            s_part[0] + s_part[1] + s_part[2] + s_part[3];
}

__global__ __launch_bounds__(256) void k_reduce(const float* __restrict__ ws,
                                                float* __restrict__ out, int count) {
    __shared__ float sred[256];
    int t = threadIdx.x;
    float s = 0.f;
    for (int i = t; i < count; i += 256) s += ws[i];
    sred[t] = s;
    __syncthreads();
    for (int o = 128; o > 0; o >>= 1) {
        if (t < o) sred[t] += sred[t + o];
        __syncthreads();
    }
    if (t == 0) out[OFF_LOGPROB] = sred[0];
}

extern "C" void kernel_launch(void* const* d_in, const int* in_sizes, int n_in,
                              void* d_out, int out_size, void* d_ws, size_t ws_size,
                              hipStream_t stream) {
    const float* x        = (const float*)d_in[0];
    const float* votes    = (const float*)d_in[1];
    const float* scales   = (const float*)d_in[2];
    const float* vpp      = (const float*)d_in[3];
    const float* presence = (const float*)d_in[4];
    const int*   nv       = (const int*)d_in[5];
    float* out = (float*)d_out;
    float* ws  = (float*)d_ws;

    dim3 g(GRID_X, B);
    k_fused<<<g, 256, 0, stream>>>(x, votes, scales, vpp, presence, nv, out, ws);
    k_reduce<<<1, 256, 0, stream>>>(ws, out, GRID_X * B);
}